// Round 2
// baseline (118.522 us; speedup 1.0000x reference)
//
#include <hip/hip_runtime.h>
#include <hip/hip_fp16.h>

typedef unsigned short u16;
typedef unsigned int u32;
typedef __attribute__((ext_vector_type(8))) short bf16x8;
typedef __attribute__((ext_vector_type(4))) float f32x4;

#define NJ 4094

__device__ __forceinline__ u16 f2bf(float f) {
  union { float f; unsigned u; } v;
  v.f = f;
  unsigned r = v.u + 0x7fffu + ((v.u >> 16) & 1u);
  return (u16)(r >> 16);
}

// pack hi16(a),hi16(b) -> u32 (a in low half), with +0x8000 round-half-up pre-added
__device__ __forceinline__ u32 pk_bf(float a, float b) {
  u32 ua = __float_as_uint(a) + 0x8000u;
  u32 ub = __float_as_uint(b) + 0x8000u;
  return __builtin_amdgcn_perm(ub, ua, 0x07060302u);  // bytes: ua.b2,ua.b3,ub.b2,ub.b3
}

// ---------------- dilated conv1d -> x2 (bf16, two layouts, j zero-padded to 4096) ----------------
// R8: 512 blocks (2 b x 256 j-tiles of 16) -> 2 blocks/CU so staging overlaps compute.
// Weight LDS layout i*195 + c*3 + tap: staging writes land bank (3i+tap + 3c) mod 32 ->
// fully spread (old (i*64+c)*3+tap layout was a ~21-way conflict: 192 % 32 == 0).
// x2n written as one 8B ushort4/thread instead of 8 scattered 2B stores.
#define WST 195
template <bool WRITE_OUT>
__global__ __launch_bounds__(256) void conv_kernel(
    const float* __restrict__ x, const float* __restrict__ w,
    const float* __restrict__ bias, u16* __restrict__ x2n, u16* __restrict__ x2T,
    float* __restrict__ out) {
  __shared__ float xs[64 * 20];      // [in_ch][20 window: j-1 .. j+18]
  __shared__ float wl[64 * WST];     // [in_ch][out_ch*3 + tap], row stride 195 (conflict-free)
  const int b = blockIdx.x >> 8, jt = blockIdx.x & 255;
  const int t = threadIdx.x;
  for (int idx = t; idx < 64 * 20; idx += 256) {
    int i = idx / 20, p = idx - i * 20;
    int jg = jt * 16 - 1 + p;          // window starts at j-1
    float v = 0.f;
    if (jg >= 0 && jg < 4096) v = x[(b * 64 + i) * 4096 + jg];
    xs[idx] = v;
  }
  for (int idx = t; idx < 64 * 64 * 3; idx += 256) {
    int c = idx / 192, r = idx - c * 192;   // coalesced read of w[c][i][tap]
    int i = r / 3, tap = r - i * 3;
    wl[i * WST + c * 3 + tap] = w[idx];
  }
  __syncthreads();
  if (WRITE_OUT) {
    for (int idx = t; idx < 64 * 16; idx += 256) {
      int i = idx >> 4, k = idx & 15;
      out[(b * 64 + i) * 4096 + jt * 16 + k] = xs[i * 20 + k + 1];
    }
  }
  const int c = t & 63, jsub = t >> 6;   // each thread: 4 consecutive j
  float bv = bias[c];
  float a0 = bv, a1 = bv, a2 = bv, a3 = bv;
  for (int i = 0; i < 64; i++) {
    const float* wr = &wl[i * WST + c * 3];   // stride-3 read: 2-way max, free
    float w0 = wr[0], w1 = wr[1], w2 = wr[2];
    const float* xr = &xs[i * 20 + jsub * 4]; // broadcast within wave (jsub uniform)
    float x0 = xr[0], x1 = xr[1], x2 = xr[2], x3 = xr[3];
    float x4 = xr[4], x5 = xr[5], x6 = xr[6], x7 = xr[7];
    a0 += w0 * x0 + w1 * x2 + w2 * x4;
    a1 += w0 * x1 + w1 * x3 + w2 * x5;
    a2 += w0 * x2 + w1 * x4 + w2 * x6;
    a3 += w0 * x3 + w1 * x5 + w2 * x7;
  }
  const int jg0 = jt * 16 + jsub * 4;
  float av[4] = {a0, a1, a2, a3};
  ushort4 hv;
  u16* hp = (u16*)&hv;
#pragma unroll
  for (int k = 0; k < 4; k++) {
    float v = (jg0 + k < NJ) ? av[k] : 0.f;   // zero-pad j=4094,4095
    hp[k] = f2bf(v);
    x2T[(b * 4096 + jg0 + k) * 64 + c] = hp[k];   // coalesced: lanes -> consecutive c
  }
  *(ushort4*)&x2n[(b * 64 + c) * 4096 + jg0] = hv;  // one 8B store (was 8x 2B scattered)
}

// ---------------- fused kernel: R6 structure (rolled loop) + R9 full af2 hoist + f16 partials.
// R5/R7 showed the full software pipeline (unroll + prefetch + hoist of NEXT-jt phase-1 A)
// trips a register cliff -> scratch spills: FETCH 9->55 MB, WRITE 32->101 MB, +20 us.
// Do NOT re-add the next-jt x2T prefetch.
// R8 (+kc0 hoist) was clean; R9 hoists kc=1 too (+8 VGPR): ALL phase-2 x2n A-fragments are
// issued before the sigmoid (they read global x2n, independent of the P LDS the barrier
// protects) so sigmoid VALU hides their L2 latency instead of stalling phase-2 entry.
// Phase 1: wave owns a 16-j strip vs ALL 64 i: D = x2T(A, 4 loads) . x1(B, regs, b=1 negated)
//          -> acc = S0-S1; sigmoid -> P rows to LDS (packed b64).
// Phase 2: D[m=c16][n=i16] = x2n(A, regs) . P(B, ds_read_b128).
// Epilogue: coalesced u16 stores of f16 partials (halves part HBM traffic vs f32; partial
// sums are O(+-10), f16 adds <=~0.05 abs error -> negligible vs bf16-score rounding).
template <bool ATOMIC>
__global__ __launch_bounds__(256, 4) void fused_kernel(
    const float* __restrict__ x, const u16* __restrict__ x2n_g,
    const u16* __restrict__ x2T_g, u16* __restrict__ part_g,
    float* __restrict__ out) {
  __shared__ u16 P[2][2 * 64 * 72];   // [buf][b*64 + i_blk][j64 pad 72]
  const int t = threadIdx.x;
  const int wave = t >> 6, lane = t & 63;
  const int q = lane >> 4, ln = lane & 15;
  const int i0 = blockIdx.x * 64;
  const int jc = blockIdx.y;          // j-chunk: 4 tiles of 64

  // block-wide stage x1 -> P[1] as [b][i64][c pad72], b=1 sign-flipped (S0-S1 fold)
  u16* xs = P[1];
#pragma unroll
  for (int rep = 0; rep < 32; rep++) {
    int idx = rep * 256 + t;
    int il = idx & 63, c = (idx >> 6) & 63, b = idx >> 12;
    float v = x[(b * 64 + c) * 4096 + i0 + il];
    if (b) v = -v;
    xs[(b * 64 + il) * 72 + c] = f2bf(v);
  }
  __syncthreads();

  // x1 B-frags for all 4 i-subtiles, both batches: B[k=c][n=i]
  bf16x8 b1[2][4][2];
#pragma unroll
  for (int b = 0; b < 2; b++)
#pragma unroll
    for (int ist = 0; ist < 4; ist++)
#pragma unroll
      for (int kc = 0; kc < 2; kc++)
        b1[b][ist][kc] = *(const bf16x8*)&xs[(b * 64 + ist * 16 + ln) * 72 + kc * 32 + q * 8];

  f32x4 acc[2][4];   // phase-2 accumulators [c-strip][i-strip]
#pragma unroll
  for (int a = 0; a < 2; a++)
#pragma unroll
    for (int bq = 0; bq < 4; bq++) acc[a][bq] = (f32x4){0.f, 0.f, 0.f, 0.f};

  const int b2 = wave >> 1, cs2 = (wave & 1) * 2;  // phase-2 wave assignment

  for (int jt = jc * 4; jt < jc * 4 + 4; jt++) {
    const int j0 = jt * 64;
    u16* Ps = P[jt & 1];
    // ---- phase 1: wave's 16-j strip x all 64 i; d accumulated with b=1 negated
    f32x4 ps[4];
#pragma unroll
    for (int ist = 0; ist < 4; ist++) ps[ist] = (f32x4){0.f, 0.f, 0.f, 0.f};
#pragma unroll
    for (int b = 0; b < 2; b++)
#pragma unroll
      for (int kc = 0; kc < 2; kc++) {
        bf16x8 af = *(const bf16x8*)&x2T_g[(b * 4096 + j0 + wave * 16 + ln) * 64 + kc * 32 + q * 8];
#pragma unroll
        for (int ist = 0; ist < 4; ist++)
          ps[ist] = __builtin_amdgcn_mfma_f32_16x16x32_bf16(af, b1[b][ist][kc], ps[ist], 0, 0, 0);
      }
    // ---- R9 hoist: issue ALL phase-2 x2n A loads now; sigmoid hides their L2 latency
    bf16x8 af2h[2][2];
#pragma unroll
    for (int kc = 0; kc < 2; kc++)
#pragma unroll
      for (int cst = 0; cst < 2; cst++)
        af2h[kc][cst] =
            *(const bf16x8*)&x2n_g[(b2 * 64 + (cs2 + cst) * 16 + ln) * 4096 + j0 + kc * 32 + q * 8];
    // ---- sigmoid: p0 = 1/(1+exp(-d)); lane rows j=wave*16+q*4+r, col i=ist*16+ln
#pragma unroll
    for (int ist = 0; ist < 4; ist++) {
      float p0[4], p1[4];
#pragma unroll
      for (int r = 0; r < 4; r++) {
        float e = __expf(-ps[ist][r]);
        p0[r] = __builtin_amdgcn_rcpf(1.f + e);
        p1[r] = 1.f - p0[r];
      }
      uint2 o0 = make_uint2(pk_bf(p0[0], p0[1]), pk_bf(p0[2], p0[3]));
      uint2 o1 = make_uint2(pk_bf(p1[0], p1[1]), pk_bf(p1[2], p1[3]));
      *(uint2*)&Ps[(0 + ist * 16 + ln) * 72 + wave * 16 + q * 4] = o0;    // b=0 rows
      *(uint2*)&Ps[(64 + ist * 16 + ln) * 72 + wave * 16 + q * 4] = o1;   // b=1 rows
    }
    __syncthreads();   // only barrier per j-tile (dbuf covers WAR)
    // ---- phase 2: D[m=c16][n=i16], A = x2n rows (hoisted regs), B = P rows (ds_read_b128)
#pragma unroll
    for (int kc = 0; kc < 2; kc++) {
      bf16x8 pb[4];
#pragma unroll
      for (int ist = 0; ist < 4; ist++)
        pb[ist] = *(const bf16x8*)&Ps[(b2 * 64 + ist * 16 + ln) * 72 + kc * 32 + q * 8];
#pragma unroll
      for (int cst = 0; cst < 2; cst++)
#pragma unroll
        for (int ist = 0; ist < 4; ist++)
          acc[cst][ist] =
              __builtin_amdgcn_mfma_f32_16x16x32_bf16(af2h[kc][cst], pb[ist], acc[cst][ist], 0, 0, 0);
    }
  }
  // ---- epilogue (coalesced: consecutive ln -> consecutive ii); f16 partials
#pragma unroll
  for (int cst = 0; cst < 2; cst++)
#pragma unroll
    for (int ist = 0; ist < 4; ist++)
#pragma unroll
      for (int r = 0; r < 4; r++) {
        int c = (cs2 + cst) * 16 + q * 4 + r;
        int ii = i0 + ist * 16 + ln;
        if (ATOMIC) {
          unsafeAtomicAdd(&out[(b2 * 64 + c) * 4096 + ii], acc[cst][ist][r]);
        } else {
          part_g[(((jc * 2 + b2) * 64 + c) << 12) + ii] =
              __half_as_ushort(__float2half(acc[cst][ist][r]));
        }
      }
}

// ---------------- out = x1 + sum_{jc} part[jc] (streaming; part is f16, accum f32) ------------
__global__ __launch_bounds__(256) void reduce_kernel(
    const float4* __restrict__ x, const u16* __restrict__ part,
    float4* __restrict__ out) {
  int i = blockIdx.x * 256 + threadIdx.x;    // over 2*64*4096/4 = 131072 float4
  float4 s = x[i];
#pragma unroll
  for (int jc = 0; jc < 16; jc++) {
    uint2 p = *(const uint2*)&part[jc * 524288 + 4 * i];   // 4 f16 partials
    const __half2* hp = (const __half2*)&p;
    float2 f0 = __half22float2(hp[0]);
    float2 f1 = __half22float2(hp[1]);
    s.x += f0.x; s.y += f0.y; s.z += f1.x; s.w += f1.y;
  }
  out[i] = s;
}

extern "C" void kernel_launch(void* const* d_in, const int* in_sizes, int n_in,
                              void* d_out, int out_size, void* d_ws, size_t ws_size,
                              hipStream_t stream) {
  const float* x = (const float*)d_in[0];
  const float* w = (const float*)d_in[1];
  const float* bias = (const float*)d_in[2];
  float* out = (float*)d_out;
  u16* x2n = (u16*)d_ws;                 // [2][64][4096] bf16 = 1 MB
  u16* x2T = x2n + 2 * 64 * 4096;        // [2][4096][64] bf16 = 1 MB
  u16* part = x2T + 2 * 64 * 4096;       // [16][2][64][4096] f16 = 16 MB

  const size_t need = 2u * 64 * 4096 * 2 * 2 + 16u * 2 * 64 * 4096 * 2;
  dim3 grid(64, 16);
  if (ws_size >= need) {
    conv_kernel<false><<<512, 256, 0, stream>>>(x, w, bias, x2n, x2T, out);
    fused_kernel<false><<<grid, 256, 0, stream>>>(x, x2n, x2T, part, out);
    reduce_kernel<<<512, 256, 0, stream>>>((const float4*)x, part, (float4*)out);
  } else {
    // fallback: atomic accumulation into out (R4 path)
    conv_kernel<true><<<512, 256, 0, stream>>>(x, w, bias, x2n, x2T, out);
    fused_kernel<true><<<grid, 256, 0, stream>>>(x, x2n, x2T, nullptr, out);
  }
}

// Round 3
// 107.405 us; speedup vs baseline: 1.1035x; 1.1035x over previous
//
#include <hip/hip_runtime.h>
#include <hip/hip_fp16.h>

typedef unsigned short u16;
typedef unsigned int u32;
typedef __attribute__((ext_vector_type(8))) short bf16x8;
typedef __attribute__((ext_vector_type(4))) float f32x4;

#define NJ 4094

__device__ __forceinline__ u16 f2bf(float f) {
  union { float f; unsigned u; } v;
  v.f = f;
  unsigned r = v.u + 0x7fffu + ((v.u >> 16) & 1u);
  return (u16)(r >> 16);
}

// pack hi16(a),hi16(b) -> u32 (a in low half), with +0x8000 round-half-up pre-added
__device__ __forceinline__ u32 pk_bf(float a, float b) {
  u32 ua = __float_as_uint(a) + 0x8000u;
  u32 ub = __float_as_uint(b) + 0x8000u;
  return __builtin_amdgcn_perm(ub, ua, 0x07060302u);  // bytes: ua.b2,ua.b3,ub.b2,ub.b3
}

// ---------------- dilated conv1d -> x2 (bf16, two layouts, j zero-padded to 4096) ----------------
// R8: 512 blocks (2 b x 256 j-tiles of 16) -> 2 blocks/CU so staging overlaps compute.
// Weight LDS layout i*195 + c*3 + tap: staging writes land bank (3i+tap + 3c) mod 32 ->
// fully spread (old (i*64+c)*3+tap layout was a ~21-way conflict: 192 % 32 == 0).
// x2n written as one 8B ushort4/thread instead of 8 scattered 2B stores.
#define WST 195
template <bool WRITE_OUT>
__global__ __launch_bounds__(256) void conv_kernel(
    const float* __restrict__ x, const float* __restrict__ w,
    const float* __restrict__ bias, u16* __restrict__ x2n, u16* __restrict__ x2T,
    float* __restrict__ out) {
  __shared__ float xs[64 * 20];      // [in_ch][20 window: j-1 .. j+18]
  __shared__ float wl[64 * WST];     // [in_ch][out_ch*3 + tap], row stride 195 (conflict-free)
  const int b = blockIdx.x >> 8, jt = blockIdx.x & 255;
  const int t = threadIdx.x;
  for (int idx = t; idx < 64 * 20; idx += 256) {
    int i = idx / 20, p = idx - i * 20;
    int jg = jt * 16 - 1 + p;          // window starts at j-1
    float v = 0.f;
    if (jg >= 0 && jg < 4096) v = x[(b * 64 + i) * 4096 + jg];
    xs[idx] = v;
  }
  for (int idx = t; idx < 64 * 64 * 3; idx += 256) {
    int c = idx / 192, r = idx - c * 192;   // coalesced read of w[c][i][tap]
    int i = r / 3, tap = r - i * 3;
    wl[i * WST + c * 3 + tap] = w[idx];
  }
  __syncthreads();
  if (WRITE_OUT) {
    for (int idx = t; idx < 64 * 16; idx += 256) {
      int i = idx >> 4, k = idx & 15;
      out[(b * 64 + i) * 4096 + jt * 16 + k] = xs[i * 20 + k + 1];
    }
  }
  const int c = t & 63, jsub = t >> 6;   // each thread: 4 consecutive j
  float bv = bias[c];
  float a0 = bv, a1 = bv, a2 = bv, a3 = bv;
  for (int i = 0; i < 64; i++) {
    const float* wr = &wl[i * WST + c * 3];   // stride-3 read: 2-way max, free
    float w0 = wr[0], w1 = wr[1], w2 = wr[2];
    const float* xr = &xs[i * 20 + jsub * 4]; // broadcast within wave (jsub uniform)
    float x0 = xr[0], x1 = xr[1], x2 = xr[2], x3 = xr[3];
    float x4 = xr[4], x5 = xr[5], x6 = xr[6], x7 = xr[7];
    a0 += w0 * x0 + w1 * x2 + w2 * x4;
    a1 += w0 * x1 + w1 * x3 + w2 * x5;
    a2 += w0 * x2 + w1 * x4 + w2 * x6;
    a3 += w0 * x3 + w1 * x5 + w2 * x7;
  }
  const int jg0 = jt * 16 + jsub * 4;
  float av[4] = {a0, a1, a2, a3};
  ushort4 hv;
  u16* hp = (u16*)&hv;
#pragma unroll
  for (int k = 0; k < 4; k++) {
    float v = (jg0 + k < NJ) ? av[k] : 0.f;   // zero-pad j=4094,4095
    hp[k] = f2bf(v);
    x2T[(b * 4096 + jg0 + k) * 64 + c] = hp[k];   // coalesced: lanes -> consecutive c
  }
  *(ushort4*)&x2n[(b * 64 + c) * 4096 + jg0] = hv;  // one 8B store (was 8x 2B scattered)
}

// ---------------- fused kernel: EXACT R1 structure (kc=0 hoist ONLY) + f16 partials.
// REGISTER CLIFF LEDGER (do not re-trip):
//   R5/R7: full pipeline (unroll + next-jt x2T prefetch)  -> spills, FETCH 9->55 MB, +20 us
//   R2(R9): hoisting BOTH kc of af2 (af2h[2][2], +8 VGPR)  -> spills, FETCH 9->47 MB,
//           WRITE->80 MB, fused 45.5 us, total +13 us.  The 128-VGPR cap (launch_bounds
//           256,4) is saturated; b1 frags alone pin 64 VGPRs.  ONLY the kc=0 pair
//           (af2k0[2], 8 VGPR) fits.  Any further hoist must remove pressure elsewhere first.
// Phase 1: wave owns a 16-j strip vs ALL 64 i: D = x2T(A, 4 loads) . x1(B, regs, b=1 negated)
//          -> acc = S0-S1; sigmoid -> P rows to LDS (packed b64).
// Phase 2: D[m=c16][n=i16] = x2n(A, global; kc=0 pre-issued) . P(B, ds_read_b128).
// Epilogue: coalesced u16 stores of f16 partials (halves part HBM traffic vs f32; partial
// sums are O(+-10), f16 adds <=~0.05 abs error -> negligible vs bf16-score rounding).
template <bool ATOMIC>
__global__ __launch_bounds__(256, 4) void fused_kernel(
    const float* __restrict__ x, const u16* __restrict__ x2n_g,
    const u16* __restrict__ x2T_g, u16* __restrict__ part_g,
    float* __restrict__ out) {
  __shared__ u16 P[2][2 * 64 * 72];   // [buf][b*64 + i_blk][j64 pad 72]
  const int t = threadIdx.x;
  const int wave = t >> 6, lane = t & 63;
  const int q = lane >> 4, ln = lane & 15;
  const int i0 = blockIdx.x * 64;
  const int jc = blockIdx.y;          // j-chunk: 4 tiles of 64

  // block-wide stage x1 -> P[1] as [b][i64][c pad72], b=1 sign-flipped (S0-S1 fold)
  u16* xs = P[1];
#pragma unroll
  for (int rep = 0; rep < 32; rep++) {
    int idx = rep * 256 + t;
    int il = idx & 63, c = (idx >> 6) & 63, b = idx >> 12;
    float v = x[(b * 64 + c) * 4096 + i0 + il];
    if (b) v = -v;
    xs[(b * 64 + il) * 72 + c] = f2bf(v);
  }
  __syncthreads();

  // x1 B-frags for all 4 i-subtiles, both batches: B[k=c][n=i]
  bf16x8 b1[2][4][2];
#pragma unroll
  for (int b = 0; b < 2; b++)
#pragma unroll
    for (int ist = 0; ist < 4; ist++)
#pragma unroll
      for (int kc = 0; kc < 2; kc++)
        b1[b][ist][kc] = *(const bf16x8*)&xs[(b * 64 + ist * 16 + ln) * 72 + kc * 32 + q * 8];

  f32x4 acc[2][4];   // phase-2 accumulators [c-strip][i-strip]
#pragma unroll
  for (int a = 0; a < 2; a++)
#pragma unroll
    for (int bq = 0; bq < 4; bq++) acc[a][bq] = (f32x4){0.f, 0.f, 0.f, 0.f};

  const int b2 = wave >> 1, cs2 = (wave & 1) * 2;  // phase-2 wave assignment

  for (int jt = jc * 4; jt < jc * 4 + 4; jt++) {
    const int j0 = jt * 64;
    u16* Ps = P[jt & 1];
    // ---- phase 1: wave's 16-j strip x all 64 i; d accumulated with b=1 negated
    f32x4 ps[4];
#pragma unroll
    for (int ist = 0; ist < 4; ist++) ps[ist] = (f32x4){0.f, 0.f, 0.f, 0.f};
#pragma unroll
    for (int b = 0; b < 2; b++)
#pragma unroll
      for (int kc = 0; kc < 2; kc++) {
        bf16x8 af = *(const bf16x8*)&x2T_g[(b * 4096 + j0 + wave * 16 + ln) * 64 + kc * 32 + q * 8];
#pragma unroll
        for (int ist = 0; ist < 4; ist++)
          ps[ist] = __builtin_amdgcn_mfma_f32_16x16x32_bf16(af, b1[b][ist][kc], ps[ist], 0, 0, 0);
      }
    // ---- kc=0 hoist ONLY (8 VGPR; kc=1 too trips the spill cliff, see ledger above)
    bf16x8 af2k0[2];
#pragma unroll
    for (int cst = 0; cst < 2; cst++)
      af2k0[cst] = *(const bf16x8*)&x2n_g[(b2 * 64 + (cs2 + cst) * 16 + ln) * 4096 + j0 + q * 8];
    // ---- sigmoid: p0 = 1/(1+exp(-d)); lane rows j=wave*16+q*4+r, col i=ist*16+ln
#pragma unroll
    for (int ist = 0; ist < 4; ist++) {
      float p0[4], p1[4];
#pragma unroll
      for (int r = 0; r < 4; r++) {
        float e = __expf(-ps[ist][r]);
        p0[r] = __builtin_amdgcn_rcpf(1.f + e);
        p1[r] = 1.f - p0[r];
      }
      uint2 o0 = make_uint2(pk_bf(p0[0], p0[1]), pk_bf(p0[2], p0[3]));
      uint2 o1 = make_uint2(pk_bf(p1[0], p1[1]), pk_bf(p1[2], p1[3]));
      *(uint2*)&Ps[(0 + ist * 16 + ln) * 72 + wave * 16 + q * 4] = o0;    // b=0 rows
      *(uint2*)&Ps[(64 + ist * 16 + ln) * 72 + wave * 16 + q * 4] = o1;   // b=1 rows
    }
    __syncthreads();   // only barrier per j-tile (dbuf covers WAR)
    // ---- phase 2: D[m=c16][n=i16], A = x2n rows (16B global), B = P rows (ds_read_b128)
#pragma unroll
    for (int kc = 0; kc < 2; kc++) {
      bf16x8 af2[2], pb[4];
#pragma unroll
      for (int cst = 0; cst < 2; cst++)
        af2[cst] = (kc == 0)
                       ? af2k0[cst]
                       : *(const bf16x8*)&x2n_g[(b2 * 64 + (cs2 + cst) * 16 + ln) * 4096 + j0 + kc * 32 + q * 8];
#pragma unroll
      for (int ist = 0; ist < 4; ist++)
        pb[ist] = *(const bf16x8*)&Ps[(b2 * 64 + ist * 16 + ln) * 72 + kc * 32 + q * 8];
#pragma unroll
      for (int cst = 0; cst < 2; cst++)
#pragma unroll
        for (int ist = 0; ist < 4; ist++)
          acc[cst][ist] =
              __builtin_amdgcn_mfma_f32_16x16x32_bf16(af2[cst], pb[ist], acc[cst][ist], 0, 0, 0);
    }
  }
  // ---- epilogue (coalesced: consecutive ln -> consecutive ii); f16 partials
#pragma unroll
  for (int cst = 0; cst < 2; cst++)
#pragma unroll
    for (int ist = 0; ist < 4; ist++)
#pragma unroll
      for (int r = 0; r < 4; r++) {
        int c = (cs2 + cst) * 16 + q * 4 + r;
        int ii = i0 + ist * 16 + ln;
        if (ATOMIC) {
          unsafeAtomicAdd(&out[(b2 * 64 + c) * 4096 + ii], acc[cst][ist][r]);
        } else {
          part_g[(((jc * 2 + b2) * 64 + c) << 12) + ii] =
              __half_as_ushort(__float2half(acc[cst][ist][r]));
        }
      }
}

// ---------------- out = x1 + sum_{jc} part[jc] (streaming; part is f16, accum f32) ------------
__global__ __launch_bounds__(256) void reduce_kernel(
    const float4* __restrict__ x, const u16* __restrict__ part,
    float4* __restrict__ out) {
  int i = blockIdx.x * 256 + threadIdx.x;    // over 2*64*4096/4 = 131072 float4
  float4 s = x[i];
#pragma unroll
  for (int jc = 0; jc < 16; jc++) {
    uint2 p = *(const uint2*)&part[jc * 524288 + 4 * i];   // 4 f16 partials
    const __half2* hp = (const __half2*)&p;
    float2 f0 = __half22float2(hp[0]);
    float2 f1 = __half22float2(hp[1]);
    s.x += f0.x; s.y += f0.y; s.z += f1.x; s.w += f1.y;
  }
  out[i] = s;
}

extern "C" void kernel_launch(void* const* d_in, const int* in_sizes, int n_in,
                              void* d_out, int out_size, void* d_ws, size_t ws_size,
                              hipStream_t stream) {
  const float* x = (const float*)d_in[0];
  const float* w = (const float*)d_in[1];
  const float* bias = (const float*)d_in[2];
  float* out = (float*)d_out;
  u16* x2n = (u16*)d_ws;                 // [2][64][4096] bf16 = 1 MB
  u16* x2T = x2n + 2 * 64 * 4096;        // [2][4096][64] bf16 = 1 MB
  u16* part = x2T + 2 * 64 * 4096;       // [16][2][64][4096] f16 = 16 MB

  const size_t need = 2u * 64 * 4096 * 2 * 2 + 16u * 2 * 64 * 4096 * 2;
  dim3 grid(64, 16);
  if (ws_size >= need) {
    conv_kernel<false><<<512, 256, 0, stream>>>(x, w, bias, x2n, x2T, out);
    fused_kernel<false><<<grid, 256, 0, stream>>>(x, x2n, x2T, part, out);
    reduce_kernel<<<512, 256, 0, stream>>>((const float4*)x, part, (float4*)out);
  } else {
    // fallback: atomic accumulation into out (R4 path)
    conv_kernel<true><<<512, 256, 0, stream>>>(x, w, bias, x2n, x2T, out);
    fused_kernel<true><<<grid, 256, 0, stream>>>(x, x2n, x2T, nullptr, out);
  }
}

// Round 4
// 101.063 us; speedup vs baseline: 1.1728x; 1.0628x over previous
//
#include <hip/hip_runtime.h>
#include <hip/hip_fp16.h>

typedef unsigned short u16;
typedef unsigned int u32;
typedef __attribute__((ext_vector_type(8))) short bf16x8;
typedef __attribute__((ext_vector_type(4))) float f32x4;

#define NJ 4094

__device__ __forceinline__ u16 f2bf(float f) {
  union { float f; unsigned u; } v;
  v.f = f;
  unsigned r = v.u + 0x7fffu + ((v.u >> 16) & 1u);
  return (u16)(r >> 16);
}

// pack hi16(a),hi16(b) -> u32 (a in low half), with +0x8000 round-half-up pre-added
__device__ __forceinline__ u32 pk_bf(float a, float b) {
  u32 ua = __float_as_uint(a) + 0x8000u;
  u32 ub = __float_as_uint(b) + 0x8000u;
  return __builtin_amdgcn_perm(ub, ua, 0x07060302u);  // bytes: ua.b2,ua.b3,ub.b2,ub.b3
}

// ---------------- dilated conv1d -> x2 (bf16, two layouts, j zero-padded to 4096) ----------------
// 512 blocks (2 b x 256 j-tiles of 16) -> 2 blocks/CU so staging overlaps compute.
// Weight LDS layout i*195 + c*3 + tap: staging writes land bank (3i+tap + 3c) mod 32 ->
// fully spread (old (i*64+c)*3+tap layout was a ~21-way conflict: 192 % 32 == 0).
// x2n written as one 8B ushort4/thread instead of 8 scattered 2B stores.
#define WST 195
template <bool WRITE_OUT>
__global__ __launch_bounds__(256) void conv_kernel(
    const float* __restrict__ x, const float* __restrict__ w,
    const float* __restrict__ bias, u16* __restrict__ x2n, u16* __restrict__ x2T,
    float* __restrict__ out) {
  __shared__ float xs[64 * 20];      // [in_ch][20 window: j-1 .. j+18]
  __shared__ float wl[64 * WST];     // [in_ch][out_ch*3 + tap], row stride 195 (conflict-free)
  const int b = blockIdx.x >> 8, jt = blockIdx.x & 255;
  const int t = threadIdx.x;
  for (int idx = t; idx < 64 * 20; idx += 256) {
    int i = idx / 20, p = idx - i * 20;
    int jg = jt * 16 - 1 + p;          // window starts at j-1
    float v = 0.f;
    if (jg >= 0 && jg < 4096) v = x[(b * 64 + i) * 4096 + jg];
    xs[idx] = v;
  }
  for (int idx = t; idx < 64 * 64 * 3; idx += 256) {
    int c = idx / 192, r = idx - c * 192;   // coalesced read of w[c][i][tap]
    int i = r / 3, tap = r - i * 3;
    wl[i * WST + c * 3 + tap] = w[idx];
  }
  __syncthreads();
  if (WRITE_OUT) {
    for (int idx = t; idx < 64 * 16; idx += 256) {
      int i = idx >> 4, k = idx & 15;
      out[(b * 64 + i) * 4096 + jt * 16 + k] = xs[i * 20 + k + 1];
    }
  }
  const int c = t & 63, jsub = t >> 6;   // each thread: 4 consecutive j
  float bv = bias[c];
  float a0 = bv, a1 = bv, a2 = bv, a3 = bv;
  for (int i = 0; i < 64; i++) {
    const float* wr = &wl[i * WST + c * 3];   // stride-3 read: 2-way max, free
    float w0 = wr[0], w1 = wr[1], w2 = wr[2];
    const float* xr = &xs[i * 20 + jsub * 4]; // broadcast within wave (jsub uniform)
    float x0 = xr[0], x1 = xr[1], x2 = xr[2], x3 = xr[3];
    float x4 = xr[4], x5 = xr[5], x6 = xr[6], x7 = xr[7];
    a0 += w0 * x0 + w1 * x2 + w2 * x4;
    a1 += w0 * x1 + w1 * x3 + w2 * x5;
    a2 += w0 * x2 + w1 * x4 + w2 * x6;
    a3 += w0 * x3 + w1 * x5 + w2 * x7;
  }
  const int jg0 = jt * 16 + jsub * 4;
  float av[4] = {a0, a1, a2, a3};
  ushort4 hv;
  u16* hp = (u16*)&hv;
#pragma unroll
  for (int k = 0; k < 4; k++) {
    float v = (jg0 + k < NJ) ? av[k] : 0.f;   // zero-pad j=4094,4095
    hp[k] = f2bf(v);
    x2T[(b * 4096 + jg0 + k) * 64 + c] = hp[k];   // coalesced: lanes -> consecutive c
  }
  *(ushort4*)&x2n[(b * 64 + c) * 4096 + jg0] = hv;  // one 8B store (was 8x 2B scattered)
}

// ---------------- fused kernel: R1 structure (kc=0 hoist ONLY) + f16 partials.
// R10: grid.y 16->8 (8 j-tiles per block) -> part halves to 8 MB; jt loop pinned
// `#pragma unroll 1` so the 8-trip count can't tempt the unroller into the spill cliff.
// REGISTER CLIFF LEDGER (do not re-trip):
//   R5/R7: full pipeline (unroll + next-jt x2T prefetch)  -> spills, FETCH 9->55 MB, +20 us
//   R2(R9): hoisting BOTH kc of af2 (af2h[2][2], +8 VGPR)  -> spills, FETCH 9->47 MB,
//           WRITE->80 MB, fused 45.5 us, total +13 us.  The 128-VGPR cap (launch_bounds
//           256,4) is saturated; b1 frags alone pin 64 VGPRs.  ONLY the kc=0 pair
//           (af2k0[2], 8 VGPR) fits.  Any further hoist must remove pressure elsewhere first.
// Phase 1: wave owns a 16-j strip vs ALL 64 i: D = x2T(A, 4 loads) . x1(B, regs, b=1 negated)
//          -> acc = S0-S1; sigmoid -> P rows to LDS (packed b64).
// Phase 2: D[m=c16][n=i16] = x2n(A, global; kc=0 pre-issued) . P(B, ds_read_b128).
// Epilogue: coalesced u16 stores of f16 partials (partial sums are O(+-10), f16 adds
// <=~0.05 abs error -> negligible vs bf16-score rounding).
template <bool ATOMIC>
__global__ __launch_bounds__(256, 4) void fused_kernel(
    const float* __restrict__ x, const u16* __restrict__ x2n_g,
    const u16* __restrict__ x2T_g, u16* __restrict__ part_g,
    float* __restrict__ out) {
  __shared__ u16 P[2][2 * 64 * 72];   // [buf][b*64 + i_blk][j64 pad 72]
  const int t = threadIdx.x;
  const int wave = t >> 6, lane = t & 63;
  const int q = lane >> 4, ln = lane & 15;
  const int i0 = blockIdx.x * 64;
  const int jc = blockIdx.y;          // j-chunk: 8 tiles of 64

  // block-wide stage x1 -> P[1] as [b][i64][c pad72], b=1 sign-flipped (S0-S1 fold)
  u16* xs = P[1];
#pragma unroll
  for (int rep = 0; rep < 32; rep++) {
    int idx = rep * 256 + t;
    int il = idx & 63, c = (idx >> 6) & 63, b = idx >> 12;
    float v = x[(b * 64 + c) * 4096 + i0 + il];
    if (b) v = -v;
    xs[(b * 64 + il) * 72 + c] = f2bf(v);
  }
  __syncthreads();

  // x1 B-frags for all 4 i-subtiles, both batches: B[k=c][n=i]
  bf16x8 b1[2][4][2];
#pragma unroll
  for (int b = 0; b < 2; b++)
#pragma unroll
    for (int ist = 0; ist < 4; ist++)
#pragma unroll
      for (int kc = 0; kc < 2; kc++)
        b1[b][ist][kc] = *(const bf16x8*)&xs[(b * 64 + ist * 16 + ln) * 72 + kc * 32 + q * 8];

  f32x4 acc[2][4];   // phase-2 accumulators [c-strip][i-strip]
#pragma unroll
  for (int a = 0; a < 2; a++)
#pragma unroll
    for (int bq = 0; bq < 4; bq++) acc[a][bq] = (f32x4){0.f, 0.f, 0.f, 0.f};

  const int b2 = wave >> 1, cs2 = (wave & 1) * 2;  // phase-2 wave assignment

#pragma unroll 1
  for (int jt = jc * 8; jt < jc * 8 + 8; jt++) {
    const int j0 = jt * 64;
    u16* Ps = P[jt & 1];
    // ---- phase 1: wave's 16-j strip x all 64 i; d accumulated with b=1 negated
    f32x4 ps[4];
#pragma unroll
    for (int ist = 0; ist < 4; ist++) ps[ist] = (f32x4){0.f, 0.f, 0.f, 0.f};
#pragma unroll
    for (int b = 0; b < 2; b++)
#pragma unroll
      for (int kc = 0; kc < 2; kc++) {
        bf16x8 af = *(const bf16x8*)&x2T_g[(b * 4096 + j0 + wave * 16 + ln) * 64 + kc * 32 + q * 8];
#pragma unroll
        for (int ist = 0; ist < 4; ist++)
          ps[ist] = __builtin_amdgcn_mfma_f32_16x16x32_bf16(af, b1[b][ist][kc], ps[ist], 0, 0, 0);
      }
    // ---- kc=0 hoist ONLY (8 VGPR; kc=1 too trips the spill cliff, see ledger above)
    bf16x8 af2k0[2];
#pragma unroll
    for (int cst = 0; cst < 2; cst++)
      af2k0[cst] = *(const bf16x8*)&x2n_g[(b2 * 64 + (cs2 + cst) * 16 + ln) * 4096 + j0 + q * 8];
    // ---- sigmoid: p0 = 1/(1+exp(-d)); lane rows j=wave*16+q*4+r, col i=ist*16+ln
#pragma unroll
    for (int ist = 0; ist < 4; ist++) {
      float p0[4], p1[4];
#pragma unroll
      for (int r = 0; r < 4; r++) {
        float e = __expf(-ps[ist][r]);
        p0[r] = __builtin_amdgcn_rcpf(1.f + e);
        p1[r] = 1.f - p0[r];
      }
      uint2 o0 = make_uint2(pk_bf(p0[0], p0[1]), pk_bf(p0[2], p0[3]));
      uint2 o1 = make_uint2(pk_bf(p1[0], p1[1]), pk_bf(p1[2], p1[3]));
      *(uint2*)&Ps[(0 + ist * 16 + ln) * 72 + wave * 16 + q * 4] = o0;    // b=0 rows
      *(uint2*)&Ps[(64 + ist * 16 + ln) * 72 + wave * 16 + q * 4] = o1;   // b=1 rows
    }
    __syncthreads();   // only barrier per j-tile (dbuf covers WAR)
    // ---- phase 2: D[m=c16][n=i16], A = x2n rows (16B global), B = P rows (ds_read_b128)
#pragma unroll
    for (int kc = 0; kc < 2; kc++) {
      bf16x8 af2[2], pb[4];
#pragma unroll
      for (int cst = 0; cst < 2; cst++)
        af2[cst] = (kc == 0)
                       ? af2k0[cst]
                       : *(const bf16x8*)&x2n_g[(b2 * 64 + (cs2 + cst) * 16 + ln) * 4096 + j0 + kc * 32 + q * 8];
#pragma unroll
      for (int ist = 0; ist < 4; ist++)
        pb[ist] = *(const bf16x8*)&Ps[(b2 * 64 + ist * 16 + ln) * 72 + kc * 32 + q * 8];
#pragma unroll
      for (int cst = 0; cst < 2; cst++)
#pragma unroll
        for (int ist = 0; ist < 4; ist++)
          acc[cst][ist] =
              __builtin_amdgcn_mfma_f32_16x16x32_bf16(af2[cst], pb[ist], acc[cst][ist], 0, 0, 0);
    }
  }
  // ---- epilogue (coalesced: consecutive ln -> consecutive ii); f16 partials
#pragma unroll
  for (int cst = 0; cst < 2; cst++)
#pragma unroll
    for (int ist = 0; ist < 4; ist++)
#pragma unroll
      for (int r = 0; r < 4; r++) {
        int c = (cs2 + cst) * 16 + q * 4 + r;
        int ii = i0 + ist * 16 + ln;
        if (ATOMIC) {
          unsafeAtomicAdd(&out[(b2 * 64 + c) * 4096 + ii], acc[cst][ist][r]);
        } else {
          part_g[(((jc * 2 + b2) * 64 + c) << 12) + ii] =
              __half_as_ushort(__float2half(acc[cst][ist][r]));
        }
      }
}

// ---------------- out = x1 + sum_{jc} part[jc] (streaming; part is f16, accum f32) ------------
__global__ __launch_bounds__(256) void reduce_kernel(
    const float4* __restrict__ x, const u16* __restrict__ part,
    float4* __restrict__ out) {
  int i = blockIdx.x * 256 + threadIdx.x;    // over 2*64*4096/4 = 131072 float4
  float4 s = x[i];
#pragma unroll
  for (int jc = 0; jc < 8; jc++) {
    uint2 p = *(const uint2*)&part[jc * 524288 + 4 * i];   // 4 f16 partials
    const __half2* hp = (const __half2*)&p;
    float2 f0 = __half22float2(hp[0]);
    float2 f1 = __half22float2(hp[1]);
    s.x += f0.x; s.y += f0.y; s.z += f1.x; s.w += f1.y;
  }
  out[i] = s;
}

extern "C" void kernel_launch(void* const* d_in, const int* in_sizes, int n_in,
                              void* d_out, int out_size, void* d_ws, size_t ws_size,
                              hipStream_t stream) {
  const float* x = (const float*)d_in[0];
  const float* w = (const float*)d_in[1];
  const float* bias = (const float*)d_in[2];
  float* out = (float*)d_out;
  u16* x2n = (u16*)d_ws;                 // [2][64][4096] bf16 = 1 MB
  u16* x2T = x2n + 2 * 64 * 4096;        // [2][4096][64] bf16 = 1 MB
  u16* part = x2T + 2 * 64 * 4096;       // [8][2][64][4096] f16 = 8 MB

  const size_t need = 2u * 64 * 4096 * 2 * 2 + 8u * 2 * 64 * 4096 * 2;
  dim3 grid(64, 8);
  if (ws_size >= need) {
    conv_kernel<false><<<512, 256, 0, stream>>>(x, w, bias, x2n, x2T, out);
    fused_kernel<false><<<grid, 256, 0, stream>>>(x, x2n, x2T, part, out);
    reduce_kernel<<<512, 256, 0, stream>>>((const float4*)x, part, (float4*)out);
  } else {
    // fallback: atomic accumulation into out (R4 path)
    conv_kernel<true><<<512, 256, 0, stream>>>(x, w, bias, x2n, x2T, out);
    fused_kernel<true><<<grid, 256, 0, stream>>>(x, x2n, x2T, nullptr, out);
  }
}